// Round 8
// baseline (3391.486 us; speedup 1.0000x reference)
//
#include <hip/hip_runtime.h>
#include <math.h>

#define N_TOK 32768
#define IN_DIM 1024
#define HID 256
#define NE 64

// ---------------------------------------------------------------------------
// Pre-pass: W1[256][1024] -> W1T[1024][256] (1 MB workspace) so the hot
// kernel can DMA W rows [k][h] into LDS linearly.
// ---------------------------------------------------------------------------
__global__ __launch_bounds__(256)
void transpose_w1(const float* __restrict__ w1, float* __restrict__ w1t)
{
    __shared__ float tile[32][33];
    const int k0 = blockIdx.x * 32;
    const int h0 = blockIdx.y * 32;
    const int j  = threadIdx.x & 31;
    const int i0 = threadIdx.x >> 5;
    #pragma unroll
    for (int r = 0; r < 4; ++r) {
        int i = i0 + r * 8;
        tile[i][j] = w1[(size_t)(h0 + i) * IN_DIM + k0 + j];
    }
    __syncthreads();
    #pragma unroll
    for (int r = 0; r < 4; ++r) {
        int i = i0 + r * 8;
        w1t[(size_t)(k0 + i) * HID + h0 + j] = tile[j][i];
    }
}

__device__ __forceinline__ void gload_lds16(const float* g, float* l)
{
    __builtin_amdgcn_global_load_lds(
        (const __attribute__((address_space(1))) void*)g,
        (__attribute__((address_space(3))) void*)l,
        16, 0, 0);
}

// ---------------------------------------------------------------------------
// Round-8: R7's dataflow (X-in-reg, W-DMA-to-LDS, conflict-free 32-slot W
// reads) with the overlap R7 lacked:
//   R7 BUG: DMA + X loads issued immediately before __syncthreads -> the
//   implied vmcnt(0) drained them cold (zero overlap, ~500cy x 32 chunks at
//   1.6 waves/SIMD). VALUBusy 43%.
//   FIX: double-buffered W (2x32KB). DMA for chunk c+1 issues at the TOP of
//   chunk c (after the barrier -> no buffer race), drains only at chunk
//   c+1's barrier -> a full chunk of FMAs (~2000 issue cyc) in flight. The
//   barrier drain is then ~free (in-order VMEM retirement: the X-use waits
//   during compute already retired the earlier DMA).
//   X: float4 xP/xQ, refilled right after last use with quad+2 (~512 cyc
//   distance), runs across chunk boundaries (X independent of barriers).
//   256-thr/64-tok blocks: grid 512, 2 blocks/CU, no tail; 8 DMA + 64 X
//   loads per thread per chunk-pair.
// Per k per wave: LDS = 2 b128 (24 cyc, CU pipe) vs 128 FMA-issue cyc
// -> ratio 0.75 with 8 waves/CU: VALU-bound.
// k-order per output element unchanged -> bit-identical outputs.
// ---------------------------------------------------------------------------
union SMem {
    float Wd[2][32][256];   // 64 KB phase A: double-buffered W chunks
    float Hs[64][256];      // 64 KB phase B: H tile [tok][hid]
};

__global__ __launch_bounds__(256, 2)
void moe_gate(const float* __restrict__ x,  const float* __restrict__ w1t,
              const float* __restrict__ b1, const float* __restrict__ w2,
              const float* __restrict__ b2, float* __restrict__ out)
{
    __shared__ SMem sm;

    const int tid = threadIdx.x;
    const int tg  = tid >> 5;       // 0..7  -> tokens tg*8 .. tg*8+7
    const int hg  = tid & 31;       // 0..31 -> hiddens {hg*4..+3, 128+hg*4..+3}
    const int t0  = blockIdx.x * 64;

    const float* xb = x + (size_t)(t0 + tg * 8) * IN_DIM;

    float acc[8][8];
    #pragma unroll
    for (int i = 0; i < 8; ++i)
        #pragma unroll
        for (int j = 0; j < 8; ++j) acc[i][j] = 0.f;

    // ---------------- phase A: H = relu(X @ W1T + b1) ----------------
    // prologue: DMA chunk 0 -> Wd[0]; X quads 0,1 -> xP,xQ
    #pragma unroll
    for (int r = 0; r < 8; ++r) {
        int slot = tid + 256 * r;
        gload_lds16(w1t + slot * 4, &sm.Wd[0][0][0] + slot * 4);
    }
    float4 xP[8], xQ[8];
    #pragma unroll
    for (int t = 0; t < 8; ++t) xP[t] = *(const float4*)(xb + (size_t)t * IN_DIM);
    #pragma unroll
    for (int t = 0; t < 8; ++t) xQ[t] = *(const float4*)(xb + (size_t)t * IN_DIM + 4);

    #pragma unroll 1
    for (int c = 0; c < 32; ++c) {
        // drains chunk-c DMA (issued a full chunk ago -> cheap) and
        // guarantees nobody still reads the buffer we're about to overwrite.
        __syncthreads();
        if (c < 31) {
            const float* wsrc = w1t + (size_t)(c + 1) * 32 * HID;
            float*       wdst = &sm.Wd[(c + 1) & 1][0][0];
            #pragma unroll
            for (int r = 0; r < 8; ++r) {
                int slot = tid + 256 * r;
                gload_lds16(wsrc + slot * 4, wdst + slot * 4);
            }
        }
        const float* Wb = &sm.Wd[c & 1][0][0] + hg * 4;   // + k*256 (+128)

        #pragma unroll
        for (int q = 0; q < 8; ++q) {
            // current X buffer: even q -> xP, odd q -> xQ (compile-time)
            #pragma unroll
            for (int kk = 0; kk < 4; ++kk) {
                const int k = q * 4 + kk;
                float4 wlo = *(const float4*)(Wb + k * 256);
                float4 whi = *(const float4*)(Wb + k * 256 + 128);
                #pragma unroll
                for (int t = 0; t < 8; ++t) {
                    const float4 xv = (q & 1) ? xQ[t] : xP[t];
                    const float xs = (kk == 0) ? xv.x : (kk == 1) ? xv.y
                                   : (kk == 2) ? xv.z : xv.w;
                    acc[t][0] = fmaf(xs, wlo.x, acc[t][0]);
                    acc[t][1] = fmaf(xs, wlo.y, acc[t][1]);
                    acc[t][2] = fmaf(xs, wlo.z, acc[t][2]);
                    acc[t][3] = fmaf(xs, wlo.w, acc[t][3]);
                    acc[t][4] = fmaf(xs, whi.x, acc[t][4]);
                    acc[t][5] = fmaf(xs, whi.y, acc[t][5]);
                    acc[t][6] = fmaf(xs, whi.z, acc[t][6]);
                    acc[t][7] = fmaf(xs, whi.w, acc[t][7]);
                }
            }
            // refill the buffer just consumed with quad q+2 (global index),
            // ~512 issue-cycles before its next use; crosses chunk
            // boundaries freely (X is barrier-independent).
            const int Gn = c * 8 + q + 2;
            if (Gn < 256) {
                if (q & 1) {
                    #pragma unroll
                    for (int t = 0; t < 8; ++t)
                        xQ[t] = *(const float4*)(xb + (size_t)t * IN_DIM + Gn * 4);
                } else {
                    #pragma unroll
                    for (int t = 0; t < 8; ++t)
                        xP[t] = *(const float4*)(xb + (size_t)t * IN_DIM + Gn * 4);
                }
            }
        }
    }

    // bias + relu (j 0..3 -> h=hg*4+j, j 4..7 -> h=128+hg*4+(j-4))
    {
        float4 bb0 = *(const float4*)(b1 + hg * 4);
        float4 bb1 = *(const float4*)(b1 + 128 + hg * 4);
        float bias1[8] = {bb0.x, bb0.y, bb0.z, bb0.w, bb1.x, bb1.y, bb1.z, bb1.w};
        #pragma unroll
        for (int i = 0; i < 8; ++i)
            #pragma unroll
            for (int j = 0; j < 8; ++j)
                acc[i][j] = fmaxf(acc[i][j] + bias1[j], 0.f);
    }

    __syncthreads();   // all waves done reading Wd before Hs overwrites it
    // dump H -> LDS [tok][hid]; b128 writes, 32 slots x 2 rows = 2-way (free)
    #pragma unroll
    for (int i = 0; i < 8; ++i) {
        *(float4*)&sm.Hs[tg * 8 + i][hg * 4] =
            make_float4(acc[i][0], acc[i][1], acc[i][2], acc[i][3]);
        *(float4*)&sm.Hs[tg * 8 + i][128 + hg * 4] =
            make_float4(acc[i][4], acc[i][5], acc[i][6], acc[i][7]);
    }
    __syncthreads();

    // ---------------- phase B: logits + top-2 + softmax (R6-proven) --------
    const int ta = tid >> 4;   // 0..15 -> tokens ta*4 .. ta*4+3
    const int e4 = tid & 15;   // 0..15 -> experts e4*4 .. e4*4+3

    const float* hp[4] = { &sm.Hs[ta * 4 + 0][0], &sm.Hs[ta * 4 + 1][0],
                           &sm.Hs[ta * 4 + 2][0], &sm.Hs[ta * 4 + 3][0] };
    const float* w2p = w2 + (size_t)(e4 * 4) * HID;

    float acc2[4][4];
    #pragma unroll
    for (int i = 0; i < 4; ++i)
        #pragma unroll
        for (int j = 0; j < 4; ++j) acc2[i][j] = 0.f;

    #pragma unroll 2
    for (int k4 = 0; k4 < 64; ++k4) {
        const int k = k4 * 4;
        float hvv[4][4], evv[4][4];
        #pragma unroll
        for (int i = 0; i < 4; ++i)
            *(float4*)&hvv[i][0] = *(const float4*)(hp[i] + k);
        #pragma unroll
        for (int j = 0; j < 4; ++j)
            *(float4*)&evv[j][0] = *(const float4*)(w2p + (size_t)j * HID + k);
        #pragma unroll
        for (int d = 0; d < 4; ++d)
            #pragma unroll
            for (int i = 0; i < 4; ++i)
                #pragma unroll
                for (int j = 0; j < 4; ++j)
                    acc2[i][j] = fmaf(hvv[i][d], evv[j][d], acc2[i][j]);
    }

    // + b2, then per-token top-2 across the 16 e4-lanes (strict total order
    // (value desc, index asc) == jax.lax.top_k; verified rounds 4-7).
    float4 b2v = *(const float4*)(b2 + e4 * 4);
    #pragma unroll
    for (int i = 0; i < 4; ++i) {
        float v[4] = {acc2[i][0] + b2v.x, acc2[i][1] + b2v.y,
                      acc2[i][2] + b2v.z, acc2[i][3] + b2v.w};
        float m1 = -INFINITY, m2 = -INFINITY;
        int i1 = 0, i2 = 0;
        #pragma unroll
        for (int j = 0; j < 4; ++j) {
            int e = e4 * 4 + j;
            if (v[j] > m1)      { m2 = m1; i2 = i1; m1 = v[j]; i1 = e; }
            else if (v[j] > m2) { m2 = v[j]; i2 = e; }
        }
        #pragma unroll
        for (int off = 1; off < 16; off <<= 1) {
            float om1 = __shfl_xor(m1, off);
            int   oi1 = __shfl_xor(i1, off);
            float om2 = __shfl_xor(m2, off);
            int   oi2 = __shfl_xor(i2, off);
            bool bwin = (om1 > m1) || (om1 == m1 && oi1 < i1);
            float c1v = bwin ? om1 : m1;  int c1i = bwin ? oi1 : i1;
            float lv  = bwin ? m1  : om1; int li  = bwin ? i1  : oi1;
            float w2v = bwin ? om2 : m2;  int w2i = bwin ? oi2 : i2;
            bool s = (lv > w2v) || (lv == w2v && li < w2i);
            m1 = c1v; i1 = c1i;
            m2 = s ? lv : w2v; i2 = s ? li : w2i;
        }
        if (e4 == 0) {
            float ex  = expf(m2 - m1);          // <= 1, no overflow
            float inv = 1.f / (1.f + ex);
            int gt = t0 + ta * 4 + i;
            out[(size_t)gt * 2 + 0] = (float)i1;
            out[(size_t)gt * 2 + 1] = (float)i2;
            out[(size_t)2 * N_TOK + (size_t)gt * 2 + 0] = inv;
            out[(size_t)2 * N_TOK + (size_t)gt * 2 + 1] = ex * inv;
        }
    }
}

extern "C" void kernel_launch(void* const* d_in, const int* in_sizes, int n_in,
                              void* d_out, int out_size, void* d_ws, size_t ws_size,
                              hipStream_t stream) {
    const float* x  = (const float*)d_in[0];  // [32768,1024]
    const float* w1 = (const float*)d_in[1];  // [256,1024]
    const float* b1 = (const float*)d_in[2];  // [256]
    const float* w2 = (const float*)d_in[3];  // [64,256]
    const float* b2 = (const float*)d_in[4];  // [64]
    float* out = (float*)d_out;               // 131072 floats: idx then gates
    float* w1t = (float*)d_ws;                // W1T [1024][256], 1 MB

    transpose_w1<<<dim3(32, 8), 256, 0, stream>>>(w1, w1t);
    moe_gate<<<N_TOK / 64, 256, 0, stream>>>(x, w1t, b1, w2, b2, out);
}

// Round 9
// 2541.618 us; speedup vs baseline: 1.3344x; 1.3344x over previous
//
#include <hip/hip_runtime.h>
#include <math.h>

#define N_TOK 32768
#define IN_DIM 1024
#define HID 256
#define NE 64

// ---------------------------------------------------------------------------
// Pre-pass: W1[256][1024] -> W1T[1024][256] (1 MB workspace) so the hot
// kernel can DMA W rows [k][h] into LDS linearly.
// ---------------------------------------------------------------------------
__global__ __launch_bounds__(256)
void transpose_w1(const float* __restrict__ w1, float* __restrict__ w1t)
{
    __shared__ float tile[32][33];
    const int k0 = blockIdx.x * 32;
    const int h0 = blockIdx.y * 32;
    const int j  = threadIdx.x & 31;
    const int i0 = threadIdx.x >> 5;
    #pragma unroll
    for (int r = 0; r < 4; ++r) {
        int i = i0 + r * 8;
        tile[i][j] = w1[(size_t)(h0 + i) * IN_DIM + k0 + j];
    }
    __syncthreads();
    #pragma unroll
    for (int r = 0; r < 4; ++r) {
        int i = i0 + r * 8;
        w1t[(size_t)(k0 + i) * HID + h0 + j] = tile[j][i];
    }
}

__device__ __forceinline__ void gload_lds16(const float* g, float* l)
{
    __builtin_amdgcn_global_load_lds(
        (const __attribute__((address_space(1))) void*)g,
        (__attribute__((address_space(3))) void*)l,
        16, 0, 0);
}

// ---------------------------------------------------------------------------
// Round-9 = R8's double-buffered-DMA schedule + R7's spill-free register
// budget.
//   R8 LESSON: float4 X buffers (64 VGPR) + acc(64) spilled at the 128
//   bucket -> 10.7 GB scratch traffic, VALUBusy 6%. R7's float2 scheme
//   compiled to 116 VGPR with no spill -> reuse it verbatim.
//   R7 LESSON: single-buffered DMA drained cold at each barrier. Fix kept
//   from R8: Wd[2] double buffer; DMA for chunk c+1 issues right after
//   chunk c's barrier (no race: barrier separates all reads of that buffer)
//   and drains at chunk c+1's barrier, a full chunk (~4096 cy) later.
//   GRID INSIGHT: grid=512 caps residency at 2 blocks/CU no matter what ->
//   64 KB LDS is free at 64-tok/256-thr geometry.
//   W reads keep the R2/R6/R7-proven conflict-free shape (32 distinct 16B
//   slots + 2-way lane broadcast; never the 64-slot/1024B R4/R5 pattern).
// Per k per wave: 2 ds_read_b128 (24 cy CU-pipe) vs 128 FMA-issue cy;
// 8 waves/CU -> LDS pipe 75% busy at VALU 100% -> VALU-bound.
// k-order per output element unchanged -> bit-identical outputs.
// ---------------------------------------------------------------------------
union SMem {
    float Wd[2][32][256];   // 64 KB phase A: double-buffered W chunks
    float Hs[64][256];      // 64 KB phase B: H tile [tok][hid]
};

__global__ __launch_bounds__(256, 2)
void moe_gate(const float* __restrict__ x,  const float* __restrict__ w1t,
              const float* __restrict__ b1, const float* __restrict__ w2,
              const float* __restrict__ b2, float* __restrict__ out)
{
    __shared__ SMem sm;

    const int tid = threadIdx.x;
    const int tg  = tid >> 5;       // 0..7  -> tokens tg*8 .. tg*8+7
    const int hg  = tid & 31;       // 0..31 -> hiddens {hg*4..+3, 128+hg*4..+3}
    const int t0  = blockIdx.x * 64;

    const float* xb = x + (size_t)(t0 + tg * 8) * IN_DIM;

    float acc[8][8];
    #pragma unroll
    for (int i = 0; i < 8; ++i)
        #pragma unroll
        for (int j = 0; j < 8; ++j) acc[i][j] = 0.f;

    // ---------------- phase A: H = relu(X @ W1T + b1) ----------------
    // prologue: DMA chunk 0 -> Wd[0]; X 2-k groups 0,1 -> xA,xB
    #pragma unroll
    for (int r = 0; r < 8; ++r) {
        int slot = tid + 256 * r;
        gload_lds16(w1t + slot * 4, &sm.Wd[0][0][0] + slot * 4);
    }
    float2 xA[8], xB[8];                       // 32 VGPR total (R7-proven)
    #pragma unroll
    for (int t = 0; t < 8; ++t) xA[t] = *(const float2*)(xb + (size_t)t * IN_DIM);
    #pragma unroll
    for (int t = 0; t < 8; ++t) xB[t] = *(const float2*)(xb + (size_t)t * IN_DIM + 2);

    #pragma unroll 1
    for (int c = 0; c < 32; ++c) {
        // drains chunk-c DMA (issued a full chunk ago -> cheap) and ensures
        // every wave finished reading the buffer the next DMA overwrites.
        __syncthreads();
        if (c < 31) {
            const float* wsrc = w1t + (size_t)(c + 1) * 32 * HID;
            float*       wdst = &sm.Wd[(c + 1) & 1][0][0];
            #pragma unroll
            for (int r = 0; r < 8; ++r) {
                int slot = tid + 256 * r;
                gload_lds16(wsrc + slot * 4, wdst + slot * 4);
            }
        }
        const float* Wb = &sm.Wd[c & 1][0][0] + hg * 4;   // + k*256 (+128)

        #pragma unroll
        for (int gg = 0; gg < 16; ++gg) {      // 2-k groups; even->xA odd->xB
            const int k = gg * 2;
            float4 wlo0 = *(const float4*)(Wb + (k + 0) * 256);
            float4 whi0 = *(const float4*)(Wb + (k + 0) * 256 + 128);
            float4 wlo1 = *(const float4*)(Wb + (k + 1) * 256);
            float4 whi1 = *(const float4*)(Wb + (k + 1) * 256 + 128);
            #pragma unroll
            for (int t = 0; t < 8; ++t) {
                const float2 xv = (gg & 1) ? xB[t] : xA[t];
                acc[t][0] = fmaf(xv.x, wlo0.x, acc[t][0]);
                acc[t][1] = fmaf(xv.x, wlo0.y, acc[t][1]);
                acc[t][2] = fmaf(xv.x, wlo0.z, acc[t][2]);
                acc[t][3] = fmaf(xv.x, wlo0.w, acc[t][3]);
                acc[t][4] = fmaf(xv.x, whi0.x, acc[t][4]);
                acc[t][5] = fmaf(xv.x, whi0.y, acc[t][5]);
                acc[t][6] = fmaf(xv.x, whi0.z, acc[t][6]);
                acc[t][7] = fmaf(xv.x, whi0.w, acc[t][7]);
            }
            #pragma unroll
            for (int t = 0; t < 8; ++t) {
                const float2 xv = (gg & 1) ? xB[t] : xA[t];
                acc[t][0] = fmaf(xv.y, wlo1.x, acc[t][0]);
                acc[t][1] = fmaf(xv.y, wlo1.y, acc[t][1]);
                acc[t][2] = fmaf(xv.y, wlo1.z, acc[t][2]);
                acc[t][3] = fmaf(xv.y, wlo1.w, acc[t][3]);
                acc[t][4] = fmaf(xv.y, whi1.x, acc[t][4]);
                acc[t][5] = fmaf(xv.y, whi1.y, acc[t][5]);
                acc[t][6] = fmaf(xv.y, whi1.z, acc[t][6]);
                acc[t][7] = fmaf(xv.y, whi1.w, acc[t][7]);
            }
            // refill the buffer just consumed with 2-k group G = c*16+gg+2
            // (~512 issue-cycles ahead of its use; crosses chunk boundaries,
            // X is barrier-independent).
            const int G = c * 16 + gg + 2;
            if (G < 512) {
                if (gg & 1) {
                    #pragma unroll
                    for (int t = 0; t < 8; ++t)
                        xB[t] = *(const float2*)(xb + (size_t)t * IN_DIM + G * 2);
                } else {
                    #pragma unroll
                    for (int t = 0; t < 8; ++t)
                        xA[t] = *(const float2*)(xb + (size_t)t * IN_DIM + G * 2);
                }
            }
        }
    }

    // bias + relu (j 0..3 -> h=hg*4+j, j 4..7 -> h=128+hg*4+(j-4))
    {
        float4 bb0 = *(const float4*)(b1 + hg * 4);
        float4 bb1 = *(const float4*)(b1 + 128 + hg * 4);
        float bias1[8] = {bb0.x, bb0.y, bb0.z, bb0.w, bb1.x, bb1.y, bb1.z, bb1.w};
        #pragma unroll
        for (int i = 0; i < 8; ++i)
            #pragma unroll
            for (int j = 0; j < 8; ++j)
                acc[i][j] = fmaxf(acc[i][j] + bias1[j], 0.f);
    }

    __syncthreads();   // all waves done reading Wd before Hs overwrites it
    // dump H -> LDS [tok][hid]; b128 writes, 32 slots x 2 rows = 2-way (free)
    #pragma unroll
    for (int i = 0; i < 8; ++i) {
        *(float4*)&sm.Hs[tg * 8 + i][hg * 4] =
            make_float4(acc[i][0], acc[i][1], acc[i][2], acc[i][3]);
        *(float4*)&sm.Hs[tg * 8 + i][128 + hg * 4] =
            make_float4(acc[i][4], acc[i][5], acc[i][6], acc[i][7]);
    }
    __syncthreads();

    // ---------------- phase B: logits + top-2 + softmax (R6/R8-proven) -----
    const int ta = tid >> 4;   // 0..15 -> tokens ta*4 .. ta*4+3
    const int e4 = tid & 15;   // 0..15 -> experts e4*4 .. e4*4+3

    const float* hp[4] = { &sm.Hs[ta * 4 + 0][0], &sm.Hs[ta * 4 + 1][0],
                           &sm.Hs[ta * 4 + 2][0], &sm.Hs[ta * 4 + 3][0] };
    const float* w2p = w2 + (size_t)(e4 * 4) * HID;

    float acc2[4][4];
    #pragma unroll
    for (int i = 0; i < 4; ++i)
        #pragma unroll
        for (int j = 0; j < 4; ++j) acc2[i][j] = 0.f;

    #pragma unroll 2
    for (int k4 = 0; k4 < 64; ++k4) {
        const int k = k4 * 4;
        float hvv[4][4], evv[4][4];
        #pragma unroll
        for (int i = 0; i < 4; ++i)
            *(float4*)&hvv[i][0] = *(const float4*)(hp[i] + k);
        #pragma unroll
        for (int j = 0; j < 4; ++j)
            *(float4*)&evv[j][0] = *(const float4*)(w2p + (size_t)j * HID + k);
        #pragma unroll
        for (int d = 0; d < 4; ++d)
            #pragma unroll
            for (int i = 0; i < 4; ++i)
                #pragma unroll
                for (int j = 0; j < 4; ++j)
                    acc2[i][j] = fmaf(hvv[i][d], evv[j][d], acc2[i][j]);
    }

    // + b2, then per-token top-2 across the 16 e4-lanes (strict total order
    // (value desc, index asc) == jax.lax.top_k; verified rounds 4-8).
    float4 b2v = *(const float4*)(b2 + e4 * 4);
    #pragma unroll
    for (int i = 0; i < 4; ++i) {
        float v[4] = {acc2[i][0] + b2v.x, acc2[i][1] + b2v.y,
                      acc2[i][2] + b2v.z, acc2[i][3] + b2v.w};
        float m1 = -INFINITY, m2 = -INFINITY;
        int i1 = 0, i2 = 0;
        #pragma unroll
        for (int j = 0; j < 4; ++j) {
            int e = e4 * 4 + j;
            if (v[j] > m1)      { m2 = m1; i2 = i1; m1 = v[j]; i1 = e; }
            else if (v[j] > m2) { m2 = v[j]; i2 = e; }
        }
        #pragma unroll
        for (int off = 1; off < 16; off <<= 1) {
            float om1 = __shfl_xor(m1, off);
            int   oi1 = __shfl_xor(i1, off);
            float om2 = __shfl_xor(m2, off);
            int   oi2 = __shfl_xor(i2, off);
            bool bwin = (om1 > m1) || (om1 == m1 && oi1 < i1);
            float c1v = bwin ? om1 : m1;  int c1i = bwin ? oi1 : i1;
            float lv  = bwin ? m1  : om1; int li  = bwin ? i1  : oi1;
            float w2v = bwin ? om2 : m2;  int w2i = bwin ? oi2 : i2;
            bool s = (lv > w2v) || (lv == w2v && li < w2i);
            m1 = c1v; i1 = c1i;
            m2 = s ? lv : w2v; i2 = s ? li : w2i;
        }
        if (e4 == 0) {
            float ex  = expf(m2 - m1);          // <= 1, no overflow
            float inv = 1.f / (1.f + ex);
            int gt = t0 + ta * 4 + i;
            out[(size_t)gt * 2 + 0] = (float)i1;
            out[(size_t)gt * 2 + 1] = (float)i2;
            out[(size_t)2 * N_TOK + (size_t)gt * 2 + 0] = inv;
            out[(size_t)2 * N_TOK + (size_t)gt * 2 + 1] = ex * inv;
        }
    }
}

extern "C" void kernel_launch(void* const* d_in, const int* in_sizes, int n_in,
                              void* d_out, int out_size, void* d_ws, size_t ws_size,
                              hipStream_t stream) {
    const float* x  = (const float*)d_in[0];  // [32768,1024]
    const float* w1 = (const float*)d_in[1];  // [256,1024]
    const float* b1 = (const float*)d_in[2];  // [256]
    const float* w2 = (const float*)d_in[3];  // [64,256]
    const float* b2 = (const float*)d_in[4];  // [64]
    float* out = (float*)d_out;               // 131072 floats: idx then gates
    float* w1t = (float*)d_ws;                // W1T [1024][256], 1 MB

    transpose_w1<<<dim3(32, 8), 256, 0, stream>>>(w1, w1t);
    moe_gate<<<N_TOK / 64, 256, 0, stream>>>(x, w1t, b1, w2, b2, out);
}

// Round 10
// 488.913 us; speedup vs baseline: 6.9368x; 5.1985x over previous
//
#include <hip/hip_runtime.h>
#include <math.h>

#define N_TOK 32768
#define IN_DIM 1024
#define HID 256
#define NE 64

// ---------------------------------------------------------------------------
// Pre-pass: W1[256][1024] -> W1T[1024][256] (1 MB workspace) so the hot
// kernel can DMA W rows [k][h] into LDS linearly.
// ---------------------------------------------------------------------------
__global__ __launch_bounds__(256)
void transpose_w1(const float* __restrict__ w1, float* __restrict__ w1t)
{
    __shared__ float tile[32][33];
    const int k0 = blockIdx.x * 32;
    const int h0 = blockIdx.y * 32;
    const int j  = threadIdx.x & 31;
    const int i0 = threadIdx.x >> 5;
    #pragma unroll
    for (int r = 0; r < 4; ++r) {
        int i = i0 + r * 8;
        tile[i][j] = w1[(size_t)(h0 + i) * IN_DIM + k0 + j];
    }
    __syncthreads();
    #pragma unroll
    for (int r = 0; r < 4; ++r) {
        int i = i0 + r * 8;
        w1t[(size_t)(k0 + i) * HID + h0 + j] = tile[j][i];
    }
}

__device__ __forceinline__ void gload_lds16(const float* g, float* l)
{
    __builtin_amdgcn_global_load_lds(
        (const __attribute__((address_space(1))) void*)g,
        (__attribute__((address_space(3))) void*)l,
        16, 0, 0);
}

// ---------------------------------------------------------------------------
// Round-10 = R9's double-buffered-DMA schedule with the register allocator
// actually allowed to hold the working set:
//   R8/R9 LESSON: __launch_bounds__(256,2) empirically caps VGPR at 128
//   (R2/R5/R8/R9 all pinned at exactly 128); the schedule needs ~140-160 ->
//   allocator spilled acc -> GBs of scratch, VALUBusy <10%.
//   KEY FACT: LDS (64KB) caps residency at 2 blocks/CU anyway, and the VGPR
//   occupancy bucket for (128,256] regs is ALSO 2 waves/SIMD -> lifting the
//   cap costs ZERO occupancy. __launch_bounds__(256,1) -> no spill, same
//   residency.
//   R9 SECONDARY LESSON: runtime `if (G < 512)` guards inside the unrolled
//   inner loop stretch X live ranges (R7, with compile-time guards, compiled
//   lean). Fix: peel the last chunk (template<LAST>) so every guard is
//   compile-time.
// Schedule (unchanged from R9):
//   - Wd[2] DMA double buffer: DMA for chunk c+1 issues right after chunk
//     c's top barrier (race-free: that barrier separates all reads of the
//     target buffer) and drains at chunk c+1's barrier, a full chunk
//     (~4000 cy) later -> the barrier's vmcnt(0) is nearly free.
//   - X: float2 xA/xB dbuf, refilled right after consumption with group+2
//     (~512 cy ahead), unconditionally in the main 31 chunks.
//   - W reads: the R2/R6/R7-proven conflict-free shape (32 distinct 16B
//     slots + 2-way lane broadcast).
// Per k per wave: 2 ds_read_b128 vs 128 FMA-issue cyc; 8 waves/CU ->
// LDS pipe ~0.84x VALU -> VALU-bound.
// k-order per output element unchanged (ascending k) -> outputs match
// rounds 2-9 bit-for-bit.
// ---------------------------------------------------------------------------
union SMem {
    float Wd[2][32][256];   // 64 KB phase A: double-buffered W chunks
    float Hs[64][256];      // 64 KB phase B: H tile [tok][hid]
};

template<bool LAST>
__device__ __forceinline__ void chunk_fma(int c, const float* __restrict__ Wb,
                                          const float* __restrict__ xb,
                                          float2 (&xA)[8], float2 (&xB)[8],
                                          float (&acc)[8][8])
{
    #pragma unroll
    for (int gg = 0; gg < 16; ++gg) {        // 2-k groups; even->xA odd->xB
        const int k = gg * 2;
        float4 wlo0 = *(const float4*)(Wb + (k + 0) * 256);
        float4 whi0 = *(const float4*)(Wb + (k + 0) * 256 + 128);
        float4 wlo1 = *(const float4*)(Wb + (k + 1) * 256);
        float4 whi1 = *(const float4*)(Wb + (k + 1) * 256 + 128);
        #pragma unroll
        for (int t = 0; t < 8; ++t) {
            const float2 xv = (gg & 1) ? xB[t] : xA[t];
            acc[t][0] = fmaf(xv.x, wlo0.x, acc[t][0]);
            acc[t][1] = fmaf(xv.x, wlo0.y, acc[t][1]);
            acc[t][2] = fmaf(xv.x, wlo0.z, acc[t][2]);
            acc[t][3] = fmaf(xv.x, wlo0.w, acc[t][3]);
            acc[t][4] = fmaf(xv.x, whi0.x, acc[t][4]);
            acc[t][5] = fmaf(xv.x, whi0.y, acc[t][5]);
            acc[t][6] = fmaf(xv.x, whi0.z, acc[t][6]);
            acc[t][7] = fmaf(xv.x, whi0.w, acc[t][7]);
            acc[t][0] = fmaf(xv.y, wlo1.x, acc[t][0]);
            acc[t][1] = fmaf(xv.y, wlo1.y, acc[t][1]);
            acc[t][2] = fmaf(xv.y, wlo1.z, acc[t][2]);
            acc[t][3] = fmaf(xv.y, wlo1.w, acc[t][3]);
            acc[t][4] = fmaf(xv.y, whi1.x, acc[t][4]);
            acc[t][5] = fmaf(xv.y, whi1.y, acc[t][5]);
            acc[t][6] = fmaf(xv.y, whi1.z, acc[t][6]);
            acc[t][7] = fmaf(xv.y, whi1.w, acc[t][7]);
        }
        // refill the consumed buffer with 2-k group G = c*16+gg+2.
        // Main chunks (c<31): always legal (G <= 497). Last chunk: only
        // gg<14 (G <= 511) -- compile-time via the template parameter.
        if (!LAST || gg < 14) {
            const int G = c * 16 + gg + 2;
            if (gg & 1) {
                #pragma unroll
                for (int t = 0; t < 8; ++t)
                    xB[t] = *(const float2*)(xb + (size_t)t * IN_DIM + G * 2);
            } else {
                #pragma unroll
                for (int t = 0; t < 8; ++t)
                    xA[t] = *(const float2*)(xb + (size_t)t * IN_DIM + G * 2);
            }
        }
    }
}

__global__ __launch_bounds__(256, 1)
void moe_gate(const float* __restrict__ x,  const float* __restrict__ w1t,
              const float* __restrict__ b1, const float* __restrict__ w2,
              const float* __restrict__ b2, float* __restrict__ out)
{
    __shared__ SMem sm;

    const int tid = threadIdx.x;
    const int tg  = tid >> 5;       // 0..7  -> tokens tg*8 .. tg*8+7
    const int hg  = tid & 31;       // 0..31 -> hiddens {hg*4..+3, 128+hg*4..+3}
    const int t0  = blockIdx.x * 64;

    const float* xb = x + (size_t)(t0 + tg * 8) * IN_DIM;

    float acc[8][8];
    #pragma unroll
    for (int i = 0; i < 8; ++i)
        #pragma unroll
        for (int j = 0; j < 8; ++j) acc[i][j] = 0.f;

    // ---------------- phase A: H = relu(X @ W1T + b1) ----------------
    // prologue: DMA chunk 0 -> Wd[0]; X 2-k groups 0,1 -> xA,xB
    #pragma unroll
    for (int r = 0; r < 8; ++r) {
        int slot = tid + 256 * r;
        gload_lds16(w1t + slot * 4, &sm.Wd[0][0][0] + slot * 4);
    }
    float2 xA[8], xB[8];                       // 32 VGPR
    #pragma unroll
    for (int t = 0; t < 8; ++t) xA[t] = *(const float2*)(xb + (size_t)t * IN_DIM);
    #pragma unroll
    for (int t = 0; t < 8; ++t) xB[t] = *(const float2*)(xb + (size_t)t * IN_DIM + 2);

    #pragma unroll 1
    for (int c = 0; c < 31; ++c) {
        // drains chunk-c DMA (issued a full chunk ago -> cheap) and ensures
        // every wave finished reading the buffer the next DMA overwrites.
        __syncthreads();
        {   // DMA chunk c+1 -> other buffer
            const float* wsrc = w1t + (size_t)(c + 1) * 32 * HID;
            float*       wdst = &sm.Wd[(c + 1) & 1][0][0];
            #pragma unroll
            for (int r = 0; r < 8; ++r) {
                int slot = tid + 256 * r;
                gload_lds16(wsrc + slot * 4, wdst + slot * 4);
            }
        }
        chunk_fma<false>(c, &sm.Wd[c & 1][0][0] + hg * 4, xb, xA, xB, acc);
    }
    __syncthreads();                     // drain chunk-31 DMA
    chunk_fma<true>(31, &sm.Wd[1][0][0] + hg * 4, xb, xA, xB, acc);

    // bias + relu (j 0..3 -> h=hg*4+j, j 4..7 -> h=128+hg*4+(j-4))
    {
        float4 bb0 = *(const float4*)(b1 + hg * 4);
        float4 bb1 = *(const float4*)(b1 + 128 + hg * 4);
        float bias1[8] = {bb0.x, bb0.y, bb0.z, bb0.w, bb1.x, bb1.y, bb1.z, bb1.w};
        #pragma unroll
        for (int i = 0; i < 8; ++i)
            #pragma unroll
            for (int j = 0; j < 8; ++j)
                acc[i][j] = fmaxf(acc[i][j] + bias1[j], 0.f);
    }

    __syncthreads();   // all waves done reading Wd before Hs overwrites it
    // dump H -> LDS [tok][hid]; b128 writes, 32 slots x 2 rows = 2-way (free)
    #pragma unroll
    for (int i = 0; i < 8; ++i) {
        *(float4*)&sm.Hs[tg * 8 + i][hg * 4] =
            make_float4(acc[i][0], acc[i][1], acc[i][2], acc[i][3]);
        *(float4*)&sm.Hs[tg * 8 + i][128 + hg * 4] =
            make_float4(acc[i][4], acc[i][5], acc[i][6], acc[i][7]);
    }
    __syncthreads();

    // ---------------- phase B: logits + top-2 + softmax (R6/R8/R9-proven) --
    const int ta = tid >> 4;   // 0..15 -> tokens ta*4 .. ta*4+3
    const int e4 = tid & 15;   // 0..15 -> experts e4*4 .. e4*4+3

    const float* hp[4] = { &sm.Hs[ta * 4 + 0][0], &sm.Hs[ta * 4 + 1][0],
                           &sm.Hs[ta * 4 + 2][0], &sm.Hs[ta * 4 + 3][0] };
    const float* w2p = w2 + (size_t)(e4 * 4) * HID;

    float acc2[4][4];
    #pragma unroll
    for (int i = 0; i < 4; ++i)
        #pragma unroll
        for (int j = 0; j < 4; ++j) acc2[i][j] = 0.f;

    #pragma unroll 2
    for (int k4 = 0; k4 < 64; ++k4) {
        const int k = k4 * 4;
        float hvv[4][4], evv[4][4];
        #pragma unroll
        for (int i = 0; i < 4; ++i)
            *(float4*)&hvv[i][0] = *(const float4*)(hp[i] + k);
        #pragma unroll
        for (int j = 0; j < 4; ++j)
            *(float4*)&evv[j][0] = *(const float4*)(w2p + (size_t)j * HID + k);
        #pragma unroll
        for (int d = 0; d < 4; ++d)
            #pragma unroll
            for (int i = 0; i < 4; ++i)
                #pragma unroll
                for (int j = 0; j < 4; ++j)
                    acc2[i][j] = fmaf(hvv[i][d], evv[j][d], acc2[i][j]);
    }

    // + b2, then per-token top-2 across the 16 e4-lanes (strict total order
    // (value desc, index asc) == jax.lax.top_k; verified rounds 4-9).
    float4 b2v = *(const float4*)(b2 + e4 * 4);
    #pragma unroll
    for (int i = 0; i < 4; ++i) {
        float v[4] = {acc2[i][0] + b2v.x, acc2[i][1] + b2v.y,
                      acc2[i][2] + b2v.z, acc2[i][3] + b2v.w};
        float m1 = -INFINITY, m2 = -INFINITY;
        int i1 = 0, i2 = 0;
        #pragma unroll
        for (int j = 0; j < 4; ++j) {
            int e = e4 * 4 + j;
            if (v[j] > m1)      { m2 = m1; i2 = i1; m1 = v[j]; i1 = e; }
            else if (v[j] > m2) { m2 = v[j]; i2 = e; }
        }
        #pragma unroll
        for (int off = 1; off < 16; off <<= 1) {
            float om1 = __shfl_xor(m1, off);
            int   oi1 = __shfl_xor(i1, off);
            float om2 = __shfl_xor(m2, off);
            int   oi2 = __shfl_xor(i2, off);
            bool bwin = (om1 > m1) || (om1 == m1 && oi1 < i1);
            float c1v = bwin ? om1 : m1;  int c1i = bwin ? oi1 : i1;
            float lv  = bwin ? m1  : om1; int li  = bwin ? i1  : oi1;
            float w2v = bwin ? om2 : m2;  int w2i = bwin ? oi2 : i2;
            bool s = (lv > w2v) || (lv == w2v && li < w2i);
            m1 = c1v; i1 = c1i;
            m2 = s ? lv : w2v; i2 = s ? li : w2i;
        }
        if (e4 == 0) {
            float ex  = expf(m2 - m1);          // <= 1, no overflow
            float inv = 1.f / (1.f + ex);
            int gt = t0 + ta * 4 + i;
            out[(size_t)gt * 2 + 0] = (float)i1;
            out[(size_t)gt * 2 + 1] = (float)i2;
            out[(size_t)2 * N_TOK + (size_t)gt * 2 + 0] = inv;
            out[(size_t)2 * N_TOK + (size_t)gt * 2 + 1] = ex * inv;
        }
    }
}

extern "C" void kernel_launch(void* const* d_in, const int* in_sizes, int n_in,
                              void* d_out, int out_size, void* d_ws, size_t ws_size,
                              hipStream_t stream) {
    const float* x  = (const float*)d_in[0];  // [32768,1024]
    const float* w1 = (const float*)d_in[1];  // [256,1024]
    const float* b1 = (const float*)d_in[2];  // [256]
    const float* w2 = (const float*)d_in[3];  // [64,256]
    const float* b2 = (const float*)d_in[4];  // [64]
    float* out = (float*)d_out;               // 131072 floats: idx then gates
    float* w1t = (float*)d_ws;                // W1T [1024][256], 1 MB

    transpose_w1<<<dim3(32, 8), 256, 0, stream>>>(w1, w1t);
    moe_gate<<<N_TOK / 64, 256, 0, stream>>>(x, w1t, b1, w2, b2, out);
}